// Round 1
// baseline (281.970 us; speedup 1.0000x reference)
//
#include <hip/hip_runtime.h>
#include <hip/hip_bf16.h>
#include <math.h>

#define BATCH 8
#define TDIM 4096
#define SDIM 1024
#define CDIM 512   // AUDIO_DIM
#define DDIM 768   // SEM_DIM
#define ADIM 128   // ATTN_DIM

typedef short s8v __attribute__((ext_vector_type(8)));   // 8 bf16 (4 VGPRs)
typedef float f4v __attribute__((ext_vector_type(4)));   // 4 fp32 acc

__device__ __forceinline__ short f2bf(float f) {
    unsigned u = __float_as_uint(f);
    u += 0x7fffu + ((u >> 16) & 1u);   // RNE
    return (short)(u >> 16);
}

__device__ __forceinline__ f4v mfma16(s8v a, s8v b, f4v c) {
    return __builtin_amdgcn_mfma_f32_16x16x32_bf16(a, b, c, 0, 0, 0);
}

// ---------------------------------------------------------------------------
// prep_w: transpose weights to bf16 [n][k] layouts in workspace
//   Wq [512][128] -> WqT [128][512]; Wk/Wv [768][128] -> [128][768];
//   Wo [128][512] -> WoT [512][128]
// ---------------------------------------------------------------------------
__global__ __launch_bounds__(256) void prep_w(
    const float* __restrict__ Wq, const float* __restrict__ Wk,
    const float* __restrict__ Wv, const float* __restrict__ Wo,
    short* __restrict__ WqT, short* __restrict__ WkT,
    short* __restrict__ WvT, short* __restrict__ WoT)
{
    int gid = blockIdx.x * 256 + threadIdx.x;   // grid=256 blocks -> 65536 threads
    {
        int k = gid >> 7, n = gid & 127;        // Wq: 512*128 = 65536
        WqT[n * 512 + k] = f2bf(Wq[gid]);
    }
    #pragma unroll
    for (int i = 0; i < 2; ++i) {               // Wk/Wv: 768*128 = 98304
        int e = gid + i * 65536;
        if (e < 98304) {
            int k = e >> 7, n = e & 127;
            WkT[n * 768 + k] = f2bf(Wk[e]);
            WvT[n * 768 + k] = f2bf(Wv[e]);
        }
    }
    {
        int k = gid >> 9, c = gid & 511;        // Wo: 128*512 = 65536
        WoT[c * 128 + k] = f2bf(Wo[gid]);
    }
}

// ---------------------------------------------------------------------------
// kv_proj: K = sem @ Wk + bk -> Kb [b][s][a] bf16
//          V = sem @ Wv + bv -> Vb [b][a][s] bf16 (pre-transposed for attn)
// grid = 128 blocks (64 rows each over flattened B*S), 256 threads
// ---------------------------------------------------------------------------
__global__ __launch_bounds__(256) void kv_proj(
    const float* __restrict__ sem,
    const short* __restrict__ WkT, const float* __restrict__ bk,
    const short* __restrict__ WvT, const float* __restrict__ bv,
    short* __restrict__ Kb, short* __restrict__ Vb)
{
    __shared__ __align__(16) short sA [64 * 40];    // [row][k32 + pad8]
    __shared__ __align__(16) short sWk[128 * 40];   // [n][k32 + pad8]
    __shared__ __align__(16) short sWv[128 * 40];
    const int tid = threadIdx.x, lane = tid & 63, wave = tid >> 6;
    const int ln15 = lane & 15, q = lane >> 4, kq = q * 8;
    const int r0 = blockIdx.x * 64;                 // row in [0, B*S)
    const int b = r0 >> 10, sbase = r0 & 1023;

    f4v accK[8], accV[8];
    #pragma unroll
    for (int j = 0; j < 8; ++j) { accK[j] = (f4v)0.0f; accV[j] = (f4v)0.0f; }

    const int srow = tid >> 2;                      // 0..63
    const int skq  = (tid & 3) * 8;                 // 0,8,16,24

    for (int kc = 0; kc < DDIM / 32; ++kc) {
        __syncthreads();
        {   // stage sem tile [64][32] fp32 -> bf16
            const float* p = sem + (size_t)(r0 + srow) * DDIM + kc * 32 + skq;
            float4 f0 = *(const float4*)p;
            float4 f1 = *(const float4*)(p + 4);
            s8v v;
            v[0]=f2bf(f0.x); v[1]=f2bf(f0.y); v[2]=f2bf(f0.z); v[3]=f2bf(f0.w);
            v[4]=f2bf(f1.x); v[5]=f2bf(f1.y); v[6]=f2bf(f1.z); v[7]=f2bf(f1.w);
            *(s8v*)&sA[srow * 40 + skq] = v;
        }
        #pragma unroll
        for (int i = 0; i < 2; ++i) {   // stage W chunks [128][32] (coalesced 16B)
            int idx8 = i * 256 + tid;
            int n = idx8 >> 2, k8 = (idx8 & 3) * 8;
            *(s8v*)&sWk[n * 40 + k8] = *(const s8v*)&WkT[(size_t)n * 768 + kc * 32 + k8];
            *(s8v*)&sWv[n * 40 + k8] = *(const s8v*)&WvT[(size_t)n * 768 + kc * 32 + k8];
        }
        __syncthreads();
        int m = wave * 16 + ln15;
        s8v a = *(const s8v*)&sA[m * 40 + kq];
        #pragma unroll
        for (int j = 0; j < 8; ++j) {
            s8v bK = *(const s8v*)&sWk[(j * 16 + ln15) * 40 + kq];
            accK[j] = mfma16(a, bK, accK[j]);
            s8v bV = *(const s8v*)&sWv[(j * 16 + ln15) * 40 + kq];
            accV[j] = mfma16(a, bV, accV[j]);
        }
    }
    // epilogue: D row=(q*4+r), col=(j*16+ln15)
    const int s_in_b = sbase + wave * 16 + q * 4;
    #pragma unroll
    for (int j = 0; j < 8; ++j) {
        int col = j * 16 + ln15;
        float biasK = bk[col], biasV = bv[col];
        #pragma unroll
        for (int r = 0; r < 4; ++r)
            Kb[((size_t)b * SDIM + s_in_b + r) * ADIM + col] = f2bf(accK[j][r] + biasK);
        unsigned p0 = (unsigned short)f2bf(accV[j][0] + biasV)
                    | ((unsigned)(unsigned short)f2bf(accV[j][1] + biasV) << 16);
        unsigned p1 = (unsigned short)f2bf(accV[j][2] + biasV)
                    | ((unsigned)(unsigned short)f2bf(accV[j][3] + biasV) << 16);
        uint2 pk; pk.x = p0; pk.y = p1;   // 4 consecutive s -> one 8B store
        *(uint2*)&Vb[((size_t)b * ADIM + col) * SDIM + s_in_b] = pk;
    }
}

// ---------------------------------------------------------------------------
// ln_q: LayerNorm over C then Q = xn @ Wq + bq, scaled by 1/sqrt(128)
// grid = B * T/32 = 1024 blocks, 256 threads; tile = 32 t
// ---------------------------------------------------------------------------
__global__ __launch_bounds__(256) void ln_q(
    const float* __restrict__ x, const float* __restrict__ lnw, const float* __restrict__ lnb,
    const short* __restrict__ WqT, const float* __restrict__ bq, short* __restrict__ Qb)
{
    __shared__ __align__(16) short xt[32 * 520];    // [t][c512 + pad8] bf16 normalized
    __shared__ __align__(16) short sWq[128 * 72];   // [n][k64 + pad8]
    __shared__ float red1[8 * 32], red2[8 * 32];
    __shared__ float smu[32], srs[32];
    const int tid = threadIdx.x, lane = tid & 63, wave = tid >> 6;
    const int ln15 = lane & 15, q = lane >> 4, kq = q * 8;
    const int b = blockIdx.x >> 7;
    const int t0 = (blockIdx.x & 127) * 32;
    const float* xb = x + (size_t)b * CDIM * TDIM;

    {   // stats pass: coalesced along t
        int tl = tid & 31, p = tid >> 5;
        float s1 = 0.f, s2 = 0.f;
        const float* pp = xb + (size_t)(p * 64) * TDIM + t0 + tl;
        #pragma unroll 4
        for (int c = 0; c < 64; ++c) { float v = pp[(size_t)c * TDIM]; s1 += v; s2 += v * v; }
        red1[p * 32 + tl] = s1; red2[p * 32 + tl] = s2;
    }
    __syncthreads();
    if (tid < 32) {
        float s1 = 0.f, s2 = 0.f;
        #pragma unroll
        for (int p = 0; p < 8; ++p) { s1 += red1[p * 32 + tid]; s2 += red2[p * 32 + tid]; }
        float mu = s1 * (1.f / 512.f);
        float var = s2 * (1.f / 512.f) - mu * mu;
        smu[tid] = mu; srs[tid] = rsqrtf(var + 1e-5f);
    }
    __syncthreads();
    #pragma unroll
    for (int i = 0; i < 16; ++i) {      // normalize + transpose (re-read: L2 hit)
        int idx = i * 256 + tid;
        int c = idx >> 3, tq = (idx & 7) * 4;
        float4 f = *(const float4*)&xb[(size_t)c * TDIM + t0 + tq];
        float w = lnw[c], bb_ = lnb[c];
        float vv[4] = { f.x, f.y, f.z, f.w };
        #pragma unroll
        for (int jj = 0; jj < 4; ++jj) {
            int t = tq + jj;
            xt[t * 520 + c] = f2bf((vv[jj] - smu[t]) * srs[t] * w + bb_);
        }
    }
    f4v acc[4];
    #pragma unroll
    for (int j = 0; j < 4; ++j) acc[j] = (f4v)0.0f;
    const int m  = (wave & 1) * 16 + ln15;   // waves split M(2) x N(2)
    const int jb = (wave >> 1) * 4;
    for (int kc = 0; kc < 8; ++kc) {         // K = 512 in chunks of 64
        __syncthreads();
        #pragma unroll
        for (int i = 0; i < 4; ++i) {
            int idx8 = i * 256 + tid;
            int n = idx8 >> 3, k8 = (idx8 & 7) * 8;
            *(s8v*)&sWq[n * 72 + k8] = *(const s8v*)&WqT[(size_t)n * 512 + kc * 64 + k8];
        }
        __syncthreads();
        #pragma unroll
        for (int kk = 0; kk < 2; ++kk) {
            s8v a = *(const s8v*)&xt[m * 520 + kc * 64 + kk * 32 + kq];
            #pragma unroll
            for (int j = 0; j < 4; ++j) {
                s8v bb = *(const s8v*)&sWq[((jb + j) * 16 + ln15) * 72 + kk * 32 + kq];
                acc[j] = mfma16(a, bb, acc[j]);
            }
        }
    }
    const float scale = 0.08838834764831845f;  // 1/sqrt(128) folded into Q
    #pragma unroll
    for (int j = 0; j < 4; ++j) {
        int col = (jb + j) * 16 + ln15;
        float bias = bq[col];
        #pragma unroll
        for (int r = 0; r < 4; ++r) {
            int t = t0 + (wave & 1) * 16 + q * 4 + r;
            Qb[((size_t)b * TDIM + t) * ADIM + col] = f2bf((acc[j][r] + bias) * scale);
        }
    }
}

// ---------------------------------------------------------------------------
// attn: flash-style, no max subtraction (scores ~N(0,1), exp safe in fp32)
// grid = B * T/64 = 512 blocks, 256 threads; S-chunks of 64
// ---------------------------------------------------------------------------
__global__ __launch_bounds__(256) void attn(
    const short* __restrict__ Qb, const short* __restrict__ Kb,
    const short* __restrict__ Vb, short* __restrict__ Cx)
{
    __shared__ __align__(16) short sQ [64 * 136];   // [t][a128 + pad8]
    __shared__ __align__(16) short sK [64 * 136];   // [s][a128 + pad8]
    __shared__ __align__(16) short sVT[128 * 72];   // [a][s64 + pad8]
    __shared__ __align__(16) short sP [64 * 72];    // [t][s64 + pad8] wave-private rows
    const int tid = threadIdx.x, lane = tid & 63, wave = tid >> 6;
    const int ln15 = lane & 15, q = lane >> 4, kq = q * 8;
    const int b = blockIdx.x >> 6;
    const int t0 = (blockIdx.x & 63) * 64;
    const int m = wave * 16 + ln15;

    #pragma unroll
    for (int i = 0; i < 4; ++i) {       // stage Q once
        int idx8 = i * 256 + tid;
        int row = idx8 >> 4, a8 = (idx8 & 15) * 8;
        *(s8v*)&sQ[row * 136 + a8] = *(const s8v*)&Qb[((size_t)b * TDIM + t0 + row) * ADIM + a8];
    }
    f4v accO[8];
    #pragma unroll
    for (int j = 0; j < 8; ++j) accO[j] = (f4v)0.0f;
    float lsum[4] = { 0.f, 0.f, 0.f, 0.f };

    for (int sc = 0; sc < SDIM / 64; ++sc) {
        __syncthreads();
        const int s0 = sc * 64;
        #pragma unroll
        for (int i = 0; i < 4; ++i) {   // K chunk [64][128]
            int idx8 = i * 256 + tid;
            int row = idx8 >> 4, a8 = (idx8 & 15) * 8;
            *(s8v*)&sK[row * 136 + a8] = *(const s8v*)&Kb[((size_t)b * SDIM + s0 + row) * ADIM + a8];
        }
        #pragma unroll
        for (int i = 0; i < 4; ++i) {   // V^T chunk [128][64] (already transposed in ws)
            int idx8 = i * 256 + tid;
            int a = idx8 >> 3, s8 = (idx8 & 7) * 8;
            *(s8v*)&sVT[a * 72 + s8] = *(const s8v*)&Vb[((size_t)b * ADIM + a) * SDIM + s0 + s8];
        }
        __syncthreads();
        // QK^T -> exp -> P(LDS, wave-private) + row-sum
        #pragma unroll
        for (int j = 0; j < 4; ++j) {
            f4v sacc = (f4v)0.0f;
            #pragma unroll
            for (int kc = 0; kc < 4; ++kc) {
                s8v a  = *(const s8v*)&sQ[m * 136 + kc * 32 + kq];
                s8v bb = *(const s8v*)&sK[(j * 16 + ln15) * 136 + kc * 32 + kq];
                sacc = mfma16(a, bb, sacc);
            }
            float ev[4];
            #pragma unroll
            for (int r = 0; r < 4; ++r) {
                ev[r] = __expf(sacc[r]);
                sP[(wave * 16 + q * 4 + r) * 72 + j * 16 + ln15] = f2bf(ev[r]);
            }
            #pragma unroll
            for (int r = 0; r < 4; ++r) {   // quad reduce (16 lanes) for row sums
                float v = ev[r];
                v += __shfl_xor(v, 1);
                v += __shfl_xor(v, 2);
                v += __shfl_xor(v, 4);
                v += __shfl_xor(v, 8);
                lsum[r] += v;
            }
        }
        // PV: A = P [t][s], B = V [s][a] via sVT (wave-private sP: no barrier)
        #pragma unroll
        for (int j = 0; j < 8; ++j) {
            #pragma unroll
            for (int kc = 0; kc < 2; ++kc) {
                s8v a  = *(const s8v*)&sP[m * 72 + kc * 32 + kq];
                s8v bb = *(const s8v*)&sVT[(j * 16 + ln15) * 72 + kc * 32 + kq];
                accO[j] = mfma16(a, bb, accO[j]);
            }
        }
    }
    #pragma unroll
    for (int j = 0; j < 8; ++j) {
        int col = j * 16 + ln15;
        #pragma unroll
        for (int r = 0; r < 4; ++r) {
            int t = t0 + wave * 16 + q * 4 + r;
            Cx[((size_t)b * TDIM + t) * ADIM + col] = f2bf(accO[j][r] / lsum[r]);
        }
    }
}

// ---------------------------------------------------------------------------
// out_proj: delta = ctx @ Wo + bo, written transposed [B][C][T] coalesced
// grid = B * (T/64) * (C/128) = 2048 blocks, 256 threads
// ---------------------------------------------------------------------------
__global__ __launch_bounds__(256) void out_proj(
    const short* __restrict__ Cx, const short* __restrict__ WoT,
    const float* __restrict__ bo, float* __restrict__ out)
{
    __shared__ __align__(16) short sCtx[64 * 136];  // [t][a128 + pad8]
    __shared__ __align__(16) char  buf[128 * 136 * 2];
    short* sWoT = (short*)buf;                      // [c128][k128 + pad8]
    float* outT = (float*)buf;                      // [c128][t64 + pad4] (reused)
    const int tid = threadIdx.x, lane = tid & 63, wave = tid >> 6;
    const int ln15 = lane & 15, q = lane >> 4, kq = q * 8;
    const int b = blockIdx.x >> 8;
    const int rem = blockIdx.x & 255;
    const int t0 = (rem & 63) * 64;
    const int c0 = (rem >> 6) * 128;

    #pragma unroll
    for (int i = 0; i < 4; ++i) {
        int idx8 = i * 256 + tid;
        int row = idx8 >> 4, a8 = (idx8 & 15) * 8;
        *(s8v*)&sCtx[row * 136 + a8] = *(const s8v*)&Cx[((size_t)b * TDIM + t0 + row) * ADIM + a8];
    }
    #pragma unroll
    for (int i = 0; i < 8; ++i) {
        int idx8 = i * 256 + tid;
        int n = idx8 >> 4, k8 = (idx8 & 15) * 8;
        *(s8v*)&sWoT[n * 136 + k8] = *(const s8v*)&WoT[(size_t)(c0 + n) * ADIM + k8];
    }
    __syncthreads();
    f4v acc[8];
    #pragma unroll
    for (int j = 0; j < 8; ++j) acc[j] = (f4v)0.0f;
    const int m = wave * 16 + ln15;
    #pragma unroll
    for (int kc = 0; kc < 4; ++kc) {
        s8v a = *(const s8v*)&sCtx[m * 136 + kc * 32 + kq];
        #pragma unroll
        for (int j = 0; j < 8; ++j) {
            s8v bb = *(const s8v*)&sWoT[(j * 16 + ln15) * 136 + kc * 32 + kq];
            acc[j] = mfma16(a, bb, acc[j]);
        }
    }
    __syncthreads();    // done reading sWoT; reuse buf as outT
    #pragma unroll
    for (int j = 0; j < 8; ++j) {
        int cl = j * 16 + ln15;
        float bias = bo[c0 + cl];
        #pragma unroll
        for (int r = 0; r < 4; ++r) {
            int tl = wave * 16 + q * 4 + r;
            outT[cl * 68 + tl] = acc[j][r] + bias;
        }
    }
    __syncthreads();
    #pragma unroll
    for (int i = 0; i < 8; ++i) {       // coalesced float4 stores along t
        int idx4 = i * 256 + tid;
        int c = idx4 >> 4, t4 = (idx4 & 15) * 4;
        float4 v = *(const float4*)&outT[c * 68 + t4];
        *(float4*)&out[((size_t)b * CDIM + c0 + c) * TDIM + t0 + t4] = v;
    }
}

// ---------------------------------------------------------------------------
extern "C" void kernel_launch(void* const* d_in, const int* in_sizes, int n_in,
                              void* d_out, int out_size, void* d_ws, size_t ws_size,
                              hipStream_t stream) {
    const float* x   = (const float*)d_in[0];
    const float* sem = (const float*)d_in[1];
    const float* lnw = (const float*)d_in[2];
    const float* lnb = (const float*)d_in[3];
    const float* Wq  = (const float*)d_in[4];
    const float* bq  = (const float*)d_in[5];
    const float* Wk  = (const float*)d_in[6];
    const float* bk  = (const float*)d_in[7];
    const float* Wv  = (const float*)d_in[8];
    const float* bv  = (const float*)d_in[9];
    const float* Wo  = (const float*)d_in[10];
    const float* bo  = (const float*)d_in[11];
    float* out = (float*)d_out;

    short* ws  = (short*)d_ws;
    short* Qb  = ws;                                    // [B][T][A]  bf16
    short* Kb  = Qb  + (size_t)BATCH * TDIM * ADIM;     // [B][S][A]
    short* Vb  = Kb  + (size_t)BATCH * SDIM * ADIM;     // [B][A][S]  (transposed)
    short* Cx  = Vb  + (size_t)BATCH * SDIM * ADIM;     // [B][T][A]
    short* WqT = Cx  + (size_t)BATCH * TDIM * ADIM;     // [128][512]
    short* WkT = WqT + 128 * 512;                       // [128][768]
    short* WvT = WkT + 128 * 768;                       // [128][768]
    short* WoT = WvT + 128 * 768;                       // [512][128]

    hipLaunchKernelGGL(prep_w,  dim3(256),  dim3(256), 0, stream, Wq, Wk, Wv, Wo, WqT, WkT, WvT, WoT);
    hipLaunchKernelGGL(kv_proj, dim3(128),  dim3(256), 0, stream, sem, WkT, bk, WvT, bv, Kb, Vb);
    hipLaunchKernelGGL(ln_q,    dim3(1024), dim3(256), 0, stream, x, lnw, lnb, WqT, bq, Qb);
    hipLaunchKernelGGL(attn,    dim3(512),  dim3(256), 0, stream, Qb, Kb, Vb, Cx);
    hipLaunchKernelGGL(out_proj,dim3(2048), dim3(256), 0, stream, Cx, WoT, bo, out);
}

// Round 2
// 234.918 us; speedup vs baseline: 1.2003x; 1.2003x over previous
//
#include <hip/hip_runtime.h>
#include <hip/hip_bf16.h>
#include <math.h>

#define BATCH 8
#define TDIM 4096
#define SDIM 1024
#define CDIM 512   // AUDIO_DIM
#define DDIM 768   // SEM_DIM
#define ADIM 128   // ATTN_DIM

typedef short s8v __attribute__((ext_vector_type(8)));   // 8 bf16 (4 VGPRs)
typedef float f4v __attribute__((ext_vector_type(4)));   // 4 fp32 acc

__device__ __forceinline__ short f2bf(float f) {
    unsigned u = __float_as_uint(f);
    u += 0x7fffu + ((u >> 16) & 1u);   // RNE
    return (short)(u >> 16);
}
__device__ __forceinline__ float bf2f(short s) {
    return __uint_as_float(((unsigned)(unsigned short)s) << 16);
}
__device__ __forceinline__ f4v mfma16(s8v a, s8v b, f4v c) {
    return __builtin_amdgcn_mfma_f32_16x16x32_bf16(a, b, c, 0, 0, 0);
}

// ---------------------------------------------------------------------------
// prep_w: transpose weights to bf16 [n][k] layouts in workspace
// ---------------------------------------------------------------------------
__global__ __launch_bounds__(256) void prep_w(
    const float* __restrict__ Wq, const float* __restrict__ Wk,
    const float* __restrict__ Wv, const float* __restrict__ Wo,
    short* __restrict__ WqT, short* __restrict__ WkT,
    short* __restrict__ WvT, short* __restrict__ WoT)
{
    int gid = blockIdx.x * 256 + threadIdx.x;
    {
        int k = gid >> 7, n = gid & 127;        // Wq: 512*128
        WqT[n * 512 + k] = f2bf(Wq[gid]);
    }
    #pragma unroll
    for (int i = 0; i < 2; ++i) {               // Wk/Wv: 768*128
        int e = gid + i * 65536;
        if (e < 98304) {
            int k = e >> 7, n = e & 127;
            WkT[n * 768 + k] = f2bf(Wk[e]);
            WvT[n * 768 + k] = f2bf(Wv[e]);
        }
    }
    {
        int k = gid >> 9, c = gid & 511;        // Wo: 128*512
        WoT[c * 128 + k] = f2bf(Wo[gid]);
    }
}

// ---------------------------------------------------------------------------
// kv_proj: K = sem @ Wk + bk -> Kb [b][s][a];  V -> Vb [b][a][s] (transposed)
// 32-row tiles -> 256 blocks (fills all CUs). Waves 0,1 compute K; 2,3 V.
// ---------------------------------------------------------------------------
__global__ __launch_bounds__(256) void kv_proj(
    const float* __restrict__ sem,
    const short* __restrict__ WkT, const float* __restrict__ bk,
    const short* __restrict__ WvT, const float* __restrict__ bv,
    short* __restrict__ Kb, short* __restrict__ Vb)
{
    __shared__ __align__(16) short sA[32 * 40];      // [row][k32 + pad8]
    __shared__ __align__(16) short sW[2][128 * 40];  // [K/V][n][k32 + pad8]
    const int tid = threadIdx.x, lane = tid & 63, wave = tid >> 6;
    const int ln15 = lane & 15, q = lane >> 4, kq = q * 8;
    const int r0 = blockIdx.x * 32;
    const int b = r0 >> 10, sbase = r0 & 1023;
    const int kv = wave >> 1;        // 0 = K, 1 = V
    const int mh = wave & 1;
    const int m  = mh * 16 + ln15;

    f4v acc[8];
    #pragma unroll
    for (int j = 0; j < 8; ++j) acc[j] = (f4v)0.0f;

    const int srow = tid >> 3;          // 0..31
    const int sk4  = (tid & 7) * 4;     // 0,4,..,28

    for (int kc = 0; kc < DDIM / 32; ++kc) {
        __syncthreads();
        {   // stage sem tile [32][32] fp32 -> bf16 (uint2 = 4 bf16)
            float4 f = *(const float4*)&sem[(size_t)(r0 + srow) * DDIM + kc * 32 + sk4];
            uint2 pk;
            pk.x = (unsigned short)f2bf(f.x) | ((unsigned)(unsigned short)f2bf(f.y) << 16);
            pk.y = (unsigned short)f2bf(f.z) | ((unsigned)(unsigned short)f2bf(f.w) << 16);
            *(uint2*)&sA[srow * 40 + sk4] = pk;
        }
        #pragma unroll
        for (int i = 0; i < 2; ++i) {   // stage Wk/Wv chunks [128][32]
            int idx8 = i * 256 + tid;
            int n = idx8 >> 2, k8 = (idx8 & 3) * 8;
            *(s8v*)&sW[0][n * 40 + k8] = *(const s8v*)&WkT[(size_t)n * 768 + kc * 32 + k8];
            *(s8v*)&sW[1][n * 40 + k8] = *(const s8v*)&WvT[(size_t)n * 768 + kc * 32 + k8];
        }
        __syncthreads();
        s8v a = *(const s8v*)&sA[m * 40 + kq];
        #pragma unroll
        for (int j = 0; j < 8; ++j) {
            s8v bb = *(const s8v*)&sW[kv][(j * 16 + ln15) * 40 + kq];
            acc[j] = mfma16(a, bb, acc[j]);
        }
    }
    const int s_in_b = sbase + mh * 16 + q * 4;
    if (kv == 0) {
        #pragma unroll
        for (int j = 0; j < 8; ++j) {
            int col = j * 16 + ln15;
            float bias = bk[col];
            #pragma unroll
            for (int r = 0; r < 4; ++r)
                Kb[((size_t)b * SDIM + s_in_b + r) * ADIM + col] = f2bf(acc[j][r] + bias);
        }
    } else {
        #pragma unroll
        for (int j = 0; j < 8; ++j) {
            int col = j * 16 + ln15;
            float bias = bv[col];
            uint2 pk;
            pk.x = (unsigned short)f2bf(acc[j][0] + bias) | ((unsigned)(unsigned short)f2bf(acc[j][1] + bias) << 16);
            pk.y = (unsigned short)f2bf(acc[j][2] + bias) | ((unsigned)(unsigned short)f2bf(acc[j][3] + bias) << 16);
            *(uint2*)&Vb[((size_t)b * ADIM + col) * SDIM + s_in_b] = pk;
        }
    }
}

// ---------------------------------------------------------------------------
// ln_q: single global read of x; fp32 stats during load; raw bf16 -> swizzled
// LDS; normalize in-LDS; fused Q-proj (scale 1/sqrt(128) folded into Q).
// grid = B * T/32 = 1024 blocks, 256 threads. LDS ~50 KB -> 3 blocks/CU.
// xt swizzle: elem (t,c) at t*512 + ((c>>3) ^ ((t>>2)&7))*8 + (c&7)
// ---------------------------------------------------------------------------
__global__ __launch_bounds__(256) void ln_q(
    const float* __restrict__ x, const float* __restrict__ lnw, const float* __restrict__ lnb,
    const short* __restrict__ WqT, const float* __restrict__ bq, short* __restrict__ Qb)
{
    __shared__ __align__(16) short xt[32 * 512];       // 32 KB
    __shared__ __align__(16) char  ubuf[128 * 72 * 2]; // sWq / reduction union
    __shared__ float smu[32], srs[32];
    short* sWq  = (short*)ubuf;
    float* red1 = (float*)ubuf;              // [32][33]
    float* red2 = (float*)(ubuf + 4224);     // [32][33]
    const int tid = threadIdx.x, lane = tid & 63, wave = tid >> 6;
    const int ln15 = lane & 15, q = lane >> 4, kq = q * 8;
    const int b = blockIdx.x >> 7;
    const int t0 = (blockIdx.x & 127) * 32;
    const float* xb = x + (size_t)b * CDIM * TDIM;

    // Pass A: read x once (float4 along t), fp32 stats, raw bf16 -> xt
    const int tq = (tid & 7) * 4;
    const int g  = tid >> 3;                 // 0..31
    float ps1[4] = {0.f,0.f,0.f,0.f}, ps2[4] = {0.f,0.f,0.f,0.f};
    #pragma unroll
    for (int i = 0; i < 16; ++i) {
        int c = i * 32 + g;
        float4 f = *(const float4*)&xb[(size_t)c * TDIM + t0 + tq];
        float vv[4] = { f.x, f.y, f.z, f.w };
        int kb = c >> 3, cl = c & 7;
        #pragma unroll
        for (int jj = 0; jj < 4; ++jj) {
            int t = tq + jj;
            ps1[jj] += vv[jj]; ps2[jj] += vv[jj] * vv[jj];
            xt[t * 512 + ((kb ^ ((t >> 2) & 7)) * 8) + cl] = f2bf(vv[jj]);
        }
    }
    #pragma unroll
    for (int jj = 0; jj < 4; ++jj) {
        red1[(tq + jj) * 33 + g] = ps1[jj];
        red2[(tq + jj) * 33 + g] = ps2[jj];
    }
    __syncthreads();
    if (tid < 32) {
        float s1 = 0.f, s2 = 0.f;
        #pragma unroll 8
        for (int gg = 0; gg < 32; ++gg) { s1 += red1[tid * 33 + gg]; s2 += red2[tid * 33 + gg]; }
        float mu = s1 * (1.f / 512.f);
        float var = s2 * (1.f / 512.f) - mu * mu;
        smu[tid] = mu; srs[tid] = rsqrtf(var + 1e-5f);
    }
    __syncthreads();
    // Pass B: normalize xt in place (per thread: one c8-block x 8 t's)
    {
        const int cb = tid & 63;
        const int c8 = cb * 8;
        float w8[8], b8[8];
        #pragma unroll
        for (int jj = 0; jj < 8; ++jj) { w8[jj] = lnw[c8 + jj]; b8[jj] = lnb[c8 + jj]; }
        #pragma unroll
        for (int i = 0; i < 8; ++i) {
            int t = i * 4 + (tid >> 6);
            float mu = smu[t], rs = srs[t];
            short* p = &xt[t * 512 + ((cb ^ ((t >> 2) & 7)) * 8)];
            s8v v = *(s8v*)p;
            #pragma unroll
            for (int jj = 0; jj < 8; ++jj)
                v[jj] = f2bf((bf2f(v[jj]) - mu) * rs * w8[jj] + b8[jj]);
            *(s8v*)p = v;
        }
    }
    // Q = xt @ WqT
    f4v acc[4];
    #pragma unroll
    for (int j = 0; j < 4; ++j) acc[j] = (f4v)0.0f;
    const int mrow = (wave & 1) * 16 + ln15;
    const int jb = (wave >> 1) * 4;
    for (int kc = 0; kc < 8; ++kc) {
        __syncthreads();
        #pragma unroll
        for (int i = 0; i < 4; ++i) {
            int idx8 = i * 256 + tid;
            int n = idx8 >> 3, k8 = (idx8 & 7) * 8;
            *(s8v*)&sWq[n * 72 + k8] = *(const s8v*)&WqT[(size_t)n * 512 + kc * 64 + k8];
        }
        __syncthreads();
        #pragma unroll
        for (int kk = 0; kk < 2; ++kk) {
            int kb = kc * 8 + kk * 4 + q;
            s8v a = *(const s8v*)&xt[mrow * 512 + ((kb ^ ((mrow >> 2) & 7)) * 8)];
            #pragma unroll
            for (int j = 0; j < 4; ++j) {
                s8v bb = *(const s8v*)&sWq[((jb + j) * 16 + ln15) * 72 + kk * 32 + kq];
                acc[j] = mfma16(a, bb, acc[j]);
            }
        }
    }
    const float scale = 0.08838834764831845f;  // 1/sqrt(128)
    #pragma unroll
    for (int j = 0; j < 4; ++j) {
        int col = (jb + j) * 16 + ln15;
        float bias = bq[col];
        #pragma unroll
        for (int r = 0; r < 4; ++r) {
            int t = t0 + (wave & 1) * 16 + q * 4 + r;
            Qb[((size_t)b * TDIM + t) * ADIM + col] = f2bf((acc[j][r] + bias) * scale);
        }
    }
}

// ---------------------------------------------------------------------------
// attn: flash-style, no max subtraction. Q frags in registers (no sQ).
// XOR-swizzled unpadded LDS tiles; double-buffered K/V with register
// prefetch; row-sums via MFMA-with-ones. 512 blocks, 2/CU, LDS 72 KB.
// ---------------------------------------------------------------------------
__global__ __launch_bounds__(256) void attn(
    const short* __restrict__ Qb, const short* __restrict__ Kb,
    const short* __restrict__ Vb, short* __restrict__ Cx)
{
    __shared__ __align__(16) short sK [2][64 * 128];  // [s][a]  kb ^= row&15
    __shared__ __align__(16) short sVT[2][128 * 64];  // [a][s]  kb ^= row&7
    __shared__ __align__(16) short sP [64 * 64];      // [t][s]  kb ^= row&7 (wave-private rows)
    const int tid = threadIdx.x, lane = tid & 63, wave = tid >> 6;
    const int ln15 = lane & 15, q = lane >> 4, kq = q * 8;
    const int b = blockIdx.x >> 6;
    const int t0 = (blockIdx.x & 63) * 64;
    const int m = wave * 16 + ln15;

    const int krow = tid >> 4, kkb = tid & 15;   // K staging: row = i*16+krow
    const int varow = tid >> 3, vkb = tid & 7;   // VT staging: row = i*32+varow

    // Q fragments straight from global into registers (once)
    s8v qf[4];
    {
        const short* qp = Qb + ((size_t)b * TDIM + t0 + m) * ADIM + kq;
        #pragma unroll
        for (int kc = 0; kc < 4; ++kc) qf[kc] = *(const s8v*)(qp + kc * 32);
    }
    s8v ones;
    #pragma unroll
    for (int j = 0; j < 8; ++j) ones[j] = (short)0x3F80;  // bf16 1.0

    f4v accO[8]; f4v accL = (f4v)0.0f;
    #pragma unroll
    for (int j = 0; j < 8; ++j) accO[j] = (f4v)0.0f;

    const short* Kbase = Kb + (size_t)b * SDIM * ADIM;
    const short* Vbase = Vb + (size_t)b * ADIM * SDIM;
    s8v rk[4], rv[4];

    #pragma unroll
    for (int i = 0; i < 4; ++i) {       // prologue: load + store chunk 0
        rk[i] = *(const s8v*)(Kbase + (size_t)(i * 16 + krow) * ADIM + kkb * 8);
        rv[i] = *(const s8v*)(Vbase + (size_t)(i * 32 + varow) * SDIM + vkb * 8);
    }
    #pragma unroll
    for (int i = 0; i < 4; ++i) {
        int r = i * 16 + krow;
        *(s8v*)&sK[0][r * 128 + ((kkb ^ (r & 15)) * 8)] = rk[i];
        int a = i * 32 + varow;
        *(s8v*)&sVT[0][a * 64 + ((vkb ^ (a & 7)) * 8)] = rv[i];
    }
    __syncthreads();

    for (int sc = 0; sc < SDIM / 64; ++sc) {
        const int cur = sc & 1;
        if (sc < 15) {                  // prefetch next chunk into registers
            const int s0n = (sc + 1) * 64;
            #pragma unroll
            for (int i = 0; i < 4; ++i) {
                rk[i] = *(const s8v*)(Kbase + (size_t)(s0n + i * 16 + krow) * ADIM + kkb * 8);
                rv[i] = *(const s8v*)(Vbase + (size_t)(i * 32 + varow) * SDIM + s0n + vkb * 8);
            }
        }
        // QK^T -> exp -> sP (wave-private rows, no block barrier needed)
        #pragma unroll
        for (int j = 0; j < 4; ++j) {
            f4v sacc = (f4v)0.0f;
            const int row = j * 16 + ln15;
            #pragma unroll
            for (int kc = 0; kc < 4; ++kc) {
                s8v bb = *(const s8v*)&sK[cur][row * 128 + (((kc * 4 + q) ^ (row & 15)) * 8)];
                sacc = mfma16(qf[kc], bb, sacc);
            }
            #pragma unroll
            for (int r = 0; r < 4; ++r) {
                float ev = __expf(sacc[r]);
                int prow = wave * 16 + q * 4 + r;
                int pcol = j * 16 + ln15;
                sP[prow * 64 + (((pcol >> 3) ^ (prow & 7)) * 8) + (pcol & 7)] = f2bf(ev);
            }
        }
        // PV + row-sum via MFMA-with-ones
        #pragma unroll
        for (int kc = 0; kc < 2; ++kc) {
            s8v pa = *(const s8v*)&sP[m * 64 + (((kc * 4 + q) ^ (m & 7)) * 8)];
            accL = mfma16(pa, ones, accL);
            #pragma unroll
            for (int j = 0; j < 8; ++j) {
                int a = j * 16 + ln15;
                s8v bb = *(const s8v*)&sVT[cur][a * 64 + (((kc * 4 + q) ^ (a & 7)) * 8)];
                accO[j] = mfma16(pa, bb, accO[j]);
            }
        }
        if (sc < 15) {                  // write prefetched chunk to other buffer
            #pragma unroll
            for (int i = 0; i < 4; ++i) {
                int r = i * 16 + krow;
                *(s8v*)&sK[cur ^ 1][r * 128 + ((kkb ^ (r & 15)) * 8)] = rk[i];
                int a = i * 32 + varow;
                *(s8v*)&sVT[cur ^ 1][a * 64 + ((vkb ^ (a & 7)) * 8)] = rv[i];
            }
        }
        __syncthreads();
    }
    #pragma unroll
    for (int r = 0; r < 4; ++r) {
        float rinv = 1.0f / accL[r];
        int t = t0 + wave * 16 + q * 4 + r;
        #pragma unroll
        for (int j = 0; j < 8; ++j) {
            int col = j * 16 + ln15;
            Cx[((size_t)b * TDIM + t) * ADIM + col] = f2bf(accO[j][r] * rinv);
        }
    }
}

// ---------------------------------------------------------------------------
// out_proj: delta = ctx @ Wo + bo, written transposed [B][C][T] coalesced
// ---------------------------------------------------------------------------
__global__ __launch_bounds__(256) void out_proj(
    const short* __restrict__ Cx, const short* __restrict__ WoT,
    const float* __restrict__ bo, float* __restrict__ out)
{
    __shared__ __align__(16) short sCtx[64 * 136];  // [t][a128 + pad8]
    __shared__ __align__(16) char  buf[128 * 136 * 2];
    short* sWoT = (short*)buf;                      // [c128][k128 + pad8]
    float* outT = (float*)buf;                      // [c128][t64 + pad4]
    const int tid = threadIdx.x, lane = tid & 63, wave = tid >> 6;
    const int ln15 = lane & 15, q = lane >> 4, kq = q * 8;
    const int b = blockIdx.x >> 8;
    const int rem = blockIdx.x & 255;
    const int t0 = (rem & 63) * 64;
    const int c0 = (rem >> 6) * 128;

    #pragma unroll
    for (int i = 0; i < 4; ++i) {
        int idx8 = i * 256 + tid;
        int row = idx8 >> 4, a8 = (idx8 & 15) * 8;
        *(s8v*)&sCtx[row * 136 + a8] = *(const s8v*)&Cx[((size_t)b * TDIM + t0 + row) * ADIM + a8];
    }
    #pragma unroll
    for (int i = 0; i < 8; ++i) {
        int idx8 = i * 256 + tid;
        int n = idx8 >> 4, k8 = (idx8 & 15) * 8;
        *(s8v*)&sWoT[n * 136 + k8] = *(const s8v*)&WoT[(size_t)(c0 + n) * ADIM + k8];
    }
    __syncthreads();
    f4v acc[8];
    #pragma unroll
    for (int j = 0; j < 8; ++j) acc[j] = (f4v)0.0f;
    const int m = wave * 16 + ln15;
    #pragma unroll
    for (int kc = 0; kc < 4; ++kc) {
        s8v a = *(const s8v*)&sCtx[m * 136 + kc * 32 + kq];
        #pragma unroll
        for (int j = 0; j < 8; ++j) {
            s8v bb = *(const s8v*)&sWoT[(j * 16 + ln15) * 136 + kc * 32 + kq];
            acc[j] = mfma16(a, bb, acc[j]);
        }
    }
    __syncthreads();    // reuse buf as outT
    #pragma unroll
    for (int j = 0; j < 8; ++j) {
        int cl = j * 16 + ln15;
        float bias = bo[c0 + cl];
        #pragma unroll
        for (int r = 0; r < 4; ++r) {
            int tl = wave * 16 + q * 4 + r;
            outT[cl * 68 + tl] = acc[j][r] + bias;
        }
    }
    __syncthreads();
    #pragma unroll
    for (int i = 0; i < 8; ++i) {
        int idx4 = i * 256 + tid;
        int c = idx4 >> 4, t4 = (idx4 & 15) * 4;
        float4 v = *(const float4*)&outT[c * 68 + t4];
        *(float4*)&out[((size_t)b * CDIM + c0 + c) * TDIM + t0 + t4] = v;
    }
}

// ---------------------------------------------------------------------------
extern "C" void kernel_launch(void* const* d_in, const int* in_sizes, int n_in,
                              void* d_out, int out_size, void* d_ws, size_t ws_size,
                              hipStream_t stream) {
    const float* x   = (const float*)d_in[0];
    const float* sem = (const float*)d_in[1];
    const float* lnw = (const float*)d_in[2];
    const float* lnb = (const float*)d_in[3];
    const float* Wq  = (const float*)d_in[4];
    const float* bq  = (const float*)d_in[5];
    const float* Wk  = (const float*)d_in[6];
    const float* bk  = (const float*)d_in[7];
    const float* Wv  = (const float*)d_in[8];
    const float* bv  = (const float*)d_in[9];
    const float* Wo  = (const float*)d_in[10];
    const float* bo  = (const float*)d_in[11];
    float* out = (float*)d_out;

    short* ws  = (short*)d_ws;
    short* Qb  = ws;                                    // [B][T][A]  bf16
    short* Kb  = Qb  + (size_t)BATCH * TDIM * ADIM;     // [B][S][A]
    short* Vb  = Kb  + (size_t)BATCH * SDIM * ADIM;     // [B][A][S]  (transposed)
    short* Cx  = Vb  + (size_t)BATCH * SDIM * ADIM;     // [B][T][A]
    short* WqT = Cx  + (size_t)BATCH * TDIM * ADIM;     // [128][512]
    short* WkT = WqT + 128 * 512;                       // [128][768]
    short* WvT = WkT + 128 * 768;                       // [128][768]
    short* WoT = WvT + 128 * 768;                       // [512][128]

    hipLaunchKernelGGL(prep_w,  dim3(256),  dim3(256), 0, stream, Wq, Wk, Wv, Wo, WqT, WkT, WvT, WoT);
    hipLaunchKernelGGL(kv_proj, dim3(256),  dim3(256), 0, stream, sem, WkT, bk, WvT, bv, Kb, Vb);
    hipLaunchKernelGGL(ln_q,    dim3(1024), dim3(256), 0, stream, x, lnw, lnb, WqT, bq, Qb);
    hipLaunchKernelGGL(attn,    dim3(512),  dim3(256), 0, stream, Qb, Kb, Vb, Cx);
    hipLaunchKernelGGL(out_proj,dim3(2048), dim3(256), 0, stream, Cx, WoT, bo, out);
}